// Round 2
// baseline (1787.346 us; speedup 1.0000x reference)
//
#include <hip/hip_runtime.h>

typedef unsigned short u16;
typedef __attribute__((ext_vector_type(4))) float f32x4;
typedef __attribute__((ext_vector_type(8))) short s16x8;

#define NND 50000      // nodes per side (NU == NI)
#define EDG 1600000    // edges per relation

__device__ __forceinline__ u16 f2b(float f) {
  union { float f; unsigned u; } c; c.f = f;
  unsigned r = c.u + 0x7fff + ((c.u >> 16) & 1);   // RNE
  return (u16)(r >> 16);
}
__device__ __forceinline__ float b2f(u16 b) {
  union { float f; unsigned u; } c; c.u = ((unsigned)b) << 16; return c.f;
}

// ---------------- zero int buffer ----------------
__global__ void k_zero(int* p, int n) {
  int i = blockIdx.x * 256 + threadIdx.x;
  if (i < n) p[i] = 0;
}

// ---------------- Wt[r][n][kk] = Wv[r][kk][n]  (bf16, 3*512*256) ----------------
__global__ void k_prepw(const float* __restrict__ Wv, u16* __restrict__ Wt) {
  int tid = blockIdx.x * 256 + threadIdx.x;
  if (tid < 3 * 512 * 256) {
    int r = tid / (512 * 256); int rem = tid - r * 512 * 256;
    int n = rem >> 8; int kk = rem & 255;
    Wt[tid] = f2b(Wv[((size_t)r * 256 + kk) * 512 + n]);
  }
}

// ---------------- fused q/k weights: FW[r][o][kk] = sum_j Wv[r][kk][j]*Wqk[r][j][o] ----------------
// o<8 -> Wq head o ; o>=8 -> Wk head o-8.  FB[r][o] = bv@Wqk + bqk.
__global__ void k_fusew(const float* __restrict__ Wv, const float* __restrict__ bv,
                        const float* __restrict__ Wq, const float* __restrict__ bq,
                        const float* __restrict__ Wk, const float* __restrict__ bk,
                        float* __restrict__ FW, float* __restrict__ FB) {
  int tid = blockIdx.x * 256 + threadIdx.x;
  if (tid < 3 * 16 * 256) {
    int r = tid >> 12, o = (tid >> 8) & 15, kk = tid & 255;
    const float* wv = Wv + ((size_t)r * 256 + kk) * 512;
    const float* wqk = (o < 8) ? (Wq + r * 512 * 8 + o) : (Wk + r * 512 * 8 + (o - 8));
    float s = 0.f;
    for (int j = 0; j < 512; j++) s += wv[j] * wqk[j * 8];
    FW[tid] = s;
  }
  if (tid < 48) {
    int r = tid / 16, o = tid % 16;
    const float* wqk = (o < 8) ? (Wq + r * 512 * 8 + o) : (Wk + r * 512 * 8 + (o - 8));
    const float* bvp = bv + r * 512;
    float s = (o < 8) ? bq[r * 8 + o] : bk[r * 8 + (o - 8)];
    for (int j = 0; j < 512; j++) s += bvp[j] * wqk[j * 8];
    FB[tid] = s;
  }
}

// ---------------- CSR build ----------------
__global__ void k_count(const int* __restrict__ d1, const int* __restrict__ d2,
                        const int* __restrict__ d3, int* __restrict__ counts) {
  int e = blockIdx.x * 256 + threadIdx.x;
  int r = blockIdx.y;
  if (e < EDG) {
    const int* d = (r == 0) ? d1 : (r == 1) ? d2 : d3;
    atomicAdd(&counts[r * NND + d[e]], 1);
  }
}

__global__ void k_scan1(const int* __restrict__ in, int* __restrict__ out,
                        int* __restrict__ btot, int n) {
  __shared__ int buf[2][1024];
  int lid = threadIdx.x;
  int gid = blockIdx.x * 1024 + lid;
  int x = (gid < n) ? in[gid] : 0;
  buf[0][lid] = x;
  __syncthreads();
  int s = 0;
  for (int off = 1; off < 1024; off <<= 1) {
    int v = buf[s][lid];
    if (lid >= off) v += buf[s][lid - off];
    buf[s ^ 1][lid] = v;
    __syncthreads();
    s ^= 1;
  }
  int incl = buf[s][lid];
  if (gid < n) out[gid] = incl - x;          // exclusive within block
  if (lid == 1023) btot[blockIdx.x] = incl;
}

__global__ void k_scan2(const int* __restrict__ btot, int* __restrict__ btot2, int nb) {
  if (threadIdx.x == 0 && blockIdx.x == 0) {
    int run = 0;
    for (int i = 0; i < nb; i++) { int t = btot[i]; btot2[i] = run; run += t; }
  }
}

__global__ void k_scan3(int* __restrict__ rp, const int* __restrict__ btot2,
                        int* __restrict__ cur, int n, int total) {
  int i = blockIdx.x * 256 + threadIdx.x;
  if (i < n) {
    int v = rp[i] + btot2[i >> 10];
    rp[i] = v; cur[i] = v;
  }
  if (i == n) rp[n] = total;
}

__global__ void k_fill(const int* __restrict__ s1, const int* __restrict__ d1,
                       const int* __restrict__ s2, const int* __restrict__ d2,
                       const int* __restrict__ s3, const int* __restrict__ d3,
                       int* __restrict__ cur, int* __restrict__ csrc) {
  int e = blockIdx.x * 256 + threadIdx.x;
  int r = blockIdx.y;
  if (e < EDG) {
    const int* d = (r == 0) ? d1 : (r == 1) ? d2 : d3;
    const int* sp = (r == 0) ? s1 : (r == 1) ? s2 : s3;
    int p = atomicAdd(&cur[r * NND + d[e]], 1);
    csrc[p] = sp[e];
  }
}

// ---------------- bf16 MFMA GEMM: C[M,512] = bf16(A_f32[M,256]) @ Bt[512,256]^T + bias ----------------
// 128x128 block tile, 4 waves (2x2), 64x64 per wave, K-step 32.
__global__ void __launch_bounds__(256) k_gemm(const float* __restrict__ A, const u16* __restrict__ Bt,
                                              const float* __restrict__ bias, u16* __restrict__ C, int M) {
  __shared__ u16 sA[128 * 40];   // row stride 40 shorts (80B: 16B-aligned)
  __shared__ u16 sB[128 * 40];
  int tid = threadIdx.x;
  int lane = tid & 63, wid = tid >> 6;
  int wm = wid >> 1, wn = wid & 1;
  int l15 = lane & 15, l4 = lane >> 4;
  int m0 = blockIdx.x * 128, n0 = blockIdx.y * 128;
  f32x4 acc[4][4] = {};
  for (int ko = 0; ko < 256; ko += 32) {
#pragma unroll
    for (int p = 0; p < 2; p++) {
      int idx = p * 256 + tid;
      int row = idx >> 2, seg = idx & 3;
      int gm = m0 + row; if (gm >= M) gm = M - 1;
      float4 a0 = *(const float4*)(A + (size_t)gm * 256 + ko + seg * 8);
      float4 a1 = *(const float4*)(A + (size_t)gm * 256 + ko + seg * 8 + 4);
      s16x8 av;
      av[0] = (short)f2b(a0.x); av[1] = (short)f2b(a0.y);
      av[2] = (short)f2b(a0.z); av[3] = (short)f2b(a0.w);
      av[4] = (short)f2b(a1.x); av[5] = (short)f2b(a1.y);
      av[6] = (short)f2b(a1.z); av[7] = (short)f2b(a1.w);
      *(s16x8*)&sA[row * 40 + seg * 8] = av;
      *(s16x8*)&sB[row * 40 + seg * 8] = *(const s16x8*)(Bt + (n0 + row) * 256 + ko + seg * 8);
    }
    __syncthreads();
    s16x8 af[4], bf[4];
#pragma unroll
    for (int i = 0; i < 4; i++) af[i] = *(const s16x8*)&sA[(wm * 64 + i * 16 + l15) * 40 + l4 * 8];
#pragma unroll
    for (int j = 0; j < 4; j++) bf[j] = *(const s16x8*)&sB[(wn * 64 + j * 16 + l15) * 40 + l4 * 8];
#pragma unroll
    for (int i = 0; i < 4; i++)
#pragma unroll
      for (int j = 0; j < 4; j++)
        acc[i][j] = __builtin_amdgcn_mfma_f32_16x16x32_bf16(af[i], bf[j], acc[i][j], 0, 0, 0);
    __syncthreads();
  }
#pragma unroll
  for (int j = 0; j < 4; j++) {
    int n = n0 + wn * 64 + j * 16 + l15;
    float bb = bias[n];
#pragma unroll
    for (int i = 0; i < 4; i++) {
      int mb = m0 + wm * 64 + i * 16 + l4 * 4;
#pragma unroll
      for (int r = 0; r < 4; r++) {
        int m = mb + r;
        if (m < M) C[(size_t)m * 512 + n] = f2b(acc[i][j][r] + bb);
      }
    }
  }
}

// ---------------- q/k logits straight from fp32 x via fused weights ----------------
__global__ void k_qk(const float* __restrict__ x, const float* __restrict__ FW,
                     const float* __restrict__ FB, float* __restrict__ qout,
                     float* __restrict__ kout, int N) {
  int lane = threadIdx.x & 63, wid = threadIdx.x >> 6;
  int stride = gridDim.x * 4;
  for (int row = blockIdx.x * 4 + wid; row < N; row += stride) {
    float4 xv = *(const float4*)(x + (size_t)row * 256 + lane * 4);
    float p[16];
#pragma unroll
    for (int o = 0; o < 16; o++) {
      float4 wv = *(const float4*)(FW + o * 256 + lane * 4);
      p[o] = xv.x * wv.x + xv.y * wv.y + xv.z * wv.z + xv.w * wv.w;
    }
#pragma unroll
    for (int off = 1; off < 64; off <<= 1)
#pragma unroll
      for (int o = 0; o < 16; o++) p[o] += __shfl_xor(p[o], off, 64);
    if (lane == 0) {
      if (qout) {
#pragma unroll
        for (int o = 0; o < 8; o++) qout[row * 8 + o] = p[o] + FB[o];
      }
      if (kout) {
#pragma unroll
        for (int o = 0; o < 8; o++) kout[row * 8 + o] = p[o + 8] + FB[o + 8];
      }
    }
  }
}

// ---------------- edge aggregation: one wave per dst node ----------------
__global__ void __launch_bounds__(256) k_edge(const int* __restrict__ rp, const int* __restrict__ csrc,
                       const float* __restrict__ q, const float* __restrict__ k,
                       const u16* __restrict__ hs, float* __restrict__ out,
                       float scale, int accum) {
  __shared__ float exw[4][64 * 8];
  __shared__ int sarr[4][64];
  int lane = threadIdx.x & 63, w = threadIdx.x >> 6;
  int dst = blockIdx.x * 4 + w;
  if (dst >= NND) return;
  int beg = rp[dst];
  int deg = rp[dst + 1] - beg;
  float qv[8];
  {
    float4 q0 = *(const float4*)(q + dst * 8);
    float4 q1 = *(const float4*)(q + dst * 8 + 4);
    qv[0] = q0.x; qv[1] = q0.y; qv[2] = q0.z; qv[3] = q0.w;
    qv[4] = q1.x; qv[5] = q1.y; qv[6] = q1.z; qv[7] = q1.w;
  }
  float dsum[8] = {0, 0, 0, 0, 0, 0, 0, 0};
  for (int base = 0; base < deg; base += 64) {
    int i = base + lane;
    if (i < deg) {
      int s = csrc[beg + i];
      float4 k0 = *(const float4*)(k + s * 8);
      float4 k1 = *(const float4*)(k + s * 8 + 4);
      float kv[8] = {k0.x, k0.y, k0.z, k0.w, k1.x, k1.y, k1.z, k1.w};
#pragma unroll
      for (int h = 0; h < 8; h++) {
        float e = qv[h] + kv[h];
        e = e > 0.f ? e : 0.2f * e;
        dsum[h] += exp2f(e * 1.44269504f);
      }
    }
  }
#pragma unroll
  for (int off = 1; off < 64; off <<= 1)
#pragma unroll
    for (int h = 0; h < 8; h++) dsum[h] += __shfl_xor(dsum[h], off, 64);
  float rden[8];
#pragma unroll
  for (int h = 0; h < 8; h++) rden[h] = dsum[h] > 0.f ? 1.f / dsum[h] : 0.f;

  float acc8[8] = {0, 0, 0, 0, 0, 0, 0, 0};
  for (int base = 0; base < deg; base += 64) {
    int i = base + lane;
    int nn = min(64, deg - base);
    if (i < deg) {
      int s = csrc[beg + i];
      sarr[w][lane] = s;
      float4 k0 = *(const float4*)(k + s * 8);
      float4 k1 = *(const float4*)(k + s * 8 + 4);
      float kv[8] = {k0.x, k0.y, k0.z, k0.w, k1.x, k1.y, k1.z, k1.w};
#pragma unroll
      for (int h = 0; h < 8; h++) {
        float e = qv[h] + kv[h];
        e = e > 0.f ? e : 0.2f * e;
        exw[w][lane * 8 + h] = exp2f(e * 1.44269504f) * rden[h];
      }
    }
    __asm__ __volatile__("s_waitcnt lgkmcnt(0)" ::: "memory");
    for (int j = 0; j < nn; j++) {
      int s = sarr[w][j];
      const u16* hp = hs + (size_t)s * 512 + lane;
      float4 e0 = *(const float4*)&exw[w][j * 8];
      float4 e1 = *(const float4*)&exw[w][j * 8 + 4];
      acc8[0] += e0.x * b2f(hp[0 * 64]);
      acc8[1] += e0.y * b2f(hp[1 * 64]);
      acc8[2] += e0.z * b2f(hp[2 * 64]);
      acc8[3] += e0.w * b2f(hp[3 * 64]);
      acc8[4] += e1.x * b2f(hp[4 * 64]);
      acc8[5] += e1.y * b2f(hp[5 * 64]);
      acc8[6] += e1.z * b2f(hp[6 * 64]);
      acc8[7] += e1.w * b2f(hp[7 * 64]);
    }
  }
  float acc = ((acc8[0] + acc8[1]) + (acc8[2] + acc8[3])) + ((acc8[4] + acc8[5]) + (acc8[6] + acc8[7]));
  acc *= scale;
  if (accum) out[dst * 64 + lane] += acc;
  else out[dst * 64 + lane] = acc;
}

extern "C" void kernel_launch(void* const* d_in, const int* in_sizes, int n_in,
                              void* d_out, int out_size, void* d_ws, size_t ws_size,
                              hipStream_t stream) {
  const float* xu = (const float*)d_in[0];
  const float* xi = (const float*)d_in[1];
  const float* Wv = (const float*)d_in[2];
  const float* bv = (const float*)d_in[3];
  const float* Wq = (const float*)d_in[4];
  const float* bq = (const float*)d_in[5];
  const float* Wk = (const float*)d_in[6];
  const float* bk = (const float*)d_in[7];
  const int* src1 = (const int*)d_in[8];
  const int* dst1 = (const int*)d_in[9];
  const int* src2 = (const int*)d_in[10];
  const int* dst2 = (const int*)d_in[11];
  const int* src3 = (const int*)d_in[12];
  const int* dst3 = (const int*)d_in[13];
  float* out_user = (float*)d_out;
  float* out_item = out_user + (size_t)NND * 64;

  char* w = (char*)d_ws;
  auto alloc = [&](size_t sz) -> char* {
    char* p = w; w += (sz + 255) & ~(size_t)255; return p;
  };
  // total ~83 MB
  u16* H    = (u16*)alloc((size_t)NND * 512 * 2);          // 51.2 MB shared h table
  u16* WT   = (u16*)alloc((size_t)3 * 512 * 256 * 2);      // 0.8 MB
  float* FW = (float*)alloc((size_t)3 * 16 * 256 * 4);     // 49 KB fused qk weights
  float* FB = (float*)alloc((size_t)3 * 16 * 4);
  float* Q0 = (float*)alloc((size_t)NND * 8 * 4);
  float* K0 = (float*)alloc((size_t)NND * 8 * 4);
  float* Q1 = (float*)alloc((size_t)NND * 8 * 4);
  float* K1 = (float*)alloc((size_t)NND * 8 * 4);
  float* Q2 = (float*)alloc((size_t)NND * 8 * 4);
  float* K2 = (float*)alloc((size_t)NND * 8 * 4);          // 9.6 MB total q/k
  int* COUNTS = (int*)alloc((size_t)3 * NND * 4);
  int* ROWPTR = (int*)alloc(((size_t)3 * NND + 1) * 4);
  int* CUR    = (int*)alloc((size_t)3 * NND * 4);
  int* BTOT   = (int*)alloc(1024);
  int* BTOT2  = (int*)alloc(1024);
  int* CSRC   = (int*)alloc((size_t)3 * EDG * 4);          // 19.2 MB
  (void)ws_size; (void)n_in; (void)in_sizes; (void)out_size;

  const int NTOT = 3 * NND;            // 150000
  // --- CSR build ---
  k_zero<<<(NTOT + 255) / 256, 256, 0, stream>>>(COUNTS, NTOT);
  k_count<<<dim3(EDG / 256, 3), 256, 0, stream>>>(dst1, dst2, dst3, COUNTS);
  k_scan1<<<(NTOT + 1023) / 1024, 1024, 0, stream>>>(COUNTS, ROWPTR, BTOT, NTOT);
  k_scan2<<<1, 64, 0, stream>>>(BTOT, BTOT2, (NTOT + 1023) / 1024);
  k_scan3<<<(NTOT + 256) / 256, 256, 0, stream>>>(ROWPTR, BTOT2, CUR, NTOT, 3 * EDG);
  k_fill<<<dim3(EDG / 256, 3), 256, 0, stream>>>(src1, dst1, src2, dst2, src3, dst3, CUR, CSRC);

  // --- weight prep ---
  k_prepw<<<(3 * 512 * 256 + 255) / 256, 256, 0, stream>>>(Wv, WT);
  k_fusew<<<48, 256, 0, stream>>>(Wv, bv, Wq, bq, Wk, bk, FW, FB);

  // --- q/k logits (direct from fp32 x, fused weights) ---
  k_qk<<<1024, 256, 0, stream>>>(xi, FW,        FB,      Q0, nullptr, NND);  // rel0 q (dst=item)
  k_qk<<<1024, 256, 0, stream>>>(xu, FW,        FB,      nullptr, K0, NND);  // rel0 k (src=user)
  k_qk<<<1024, 256, 0, stream>>>(xu, FW + 4096, FB + 16, Q1, nullptr, NND);  // rel1 q (dst=user)
  k_qk<<<1024, 256, 0, stream>>>(xi, FW + 4096, FB + 16, nullptr, K1, NND);  // rel1 k (src=item)
  k_qk<<<1024, 256, 0, stream>>>(xu, FW + 8192, FB + 32, Q2, K2, NND);       // rel2 (user->user)

  // --- per relation: GEMM into shared H, then edge aggregation ---
  dim3 gg((NND + 127) / 128, 4);
  k_gemm<<<gg, 256, 0, stream>>>(xu, WT,                 bv,        H, NND);
  k_edge<<<NND / 4, 256, 0, stream>>>(ROWPTR,           CSRC, Q0, K0, H, out_item, 0.125f,  0);
  k_gemm<<<gg, 256, 0, stream>>>(xi, WT + 512 * 256,     bv + 512,  H, NND);
  k_edge<<<NND / 4, 256, 0, stream>>>(ROWPTR + NND,     CSRC, Q1, K1, H, out_user, 0.0625f, 0);
  k_gemm<<<gg, 256, 0, stream>>>(xu, WT + 2 * 512 * 256, bv + 1024, H, NND);
  k_edge<<<NND / 4, 256, 0, stream>>>(ROWPTR + 2 * NND, CSRC, Q2, K2, H, out_user, 0.0625f, 1);
}

// Round 3
// 1278.752 us; speedup vs baseline: 1.3977x; 1.3977x over previous
//
#include <hip/hip_runtime.h>

typedef unsigned short u16;
typedef __attribute__((ext_vector_type(4))) float f32x4;
typedef __attribute__((ext_vector_type(8))) short s16x8;

#define NND 50000      // nodes per side (NU == NI)
#define EDG 1600000    // edges per relation
#define NBK 391        // buckets per relation = ceil(NND/128)
#define TOTB (3 * NBK)
#define TS 4096        // edges per scatter tile

__device__ __forceinline__ u16 f2b(float f) {
  union { float f; unsigned u; } c; c.f = f;
  unsigned r = c.u + 0x7fff + ((c.u >> 16) & 1);   // RNE
  return (u16)(r >> 16);
}
__device__ __forceinline__ float b2f(u16 b) {
  union { float f; unsigned u; } c; c.u = ((unsigned)b) << 16; return c.f;
}

// ---------------- zero int buffer ----------------
__global__ void k_zero(int* p, int n) {
  int i = blockIdx.x * 256 + threadIdx.x;
  if (i < n) p[i] = 0;
}

// ---------------- Wt[r][n][kk] = Wv[r][kk][n]  (bf16, 3*512*256) ----------------
__global__ void k_prepw(const float* __restrict__ Wv, u16* __restrict__ Wt) {
  int tid = blockIdx.x * 256 + threadIdx.x;
  if (tid < 3 * 512 * 256) {
    int r = tid / (512 * 256); int rem = tid - r * 512 * 256;
    int n = rem >> 8; int kk = rem & 255;
    Wt[tid] = f2b(Wv[((size_t)r * 256 + kk) * 512 + n]);
  }
}

// ---------------- fused q/k weights: FW[r][o][kk] = sum_j Wv[r][kk][j]*Wqk[r][j][o] ----------------
__global__ void k_fusew(const float* __restrict__ Wv, const float* __restrict__ bv,
                        const float* __restrict__ Wq, const float* __restrict__ bq,
                        const float* __restrict__ Wk, const float* __restrict__ bk,
                        float* __restrict__ FW, float* __restrict__ FB) {
  int tid = blockIdx.x * 256 + threadIdx.x;
  if (tid < 3 * 16 * 256) {
    int r = tid >> 12, o = (tid >> 8) & 15, kk = tid & 255;
    const float* wv = Wv + ((size_t)r * 256 + kk) * 512;
    const float* wqk = (o < 8) ? (Wq + r * 512 * 8 + o) : (Wk + r * 512 * 8 + (o - 8));
    float s = 0.f;
    for (int j = 0; j < 512; j++) s += wv[j] * wqk[j * 8];
    FW[tid] = s;
  }
  if (tid < 48) {
    int r = tid / 16, o = tid % 16;
    const float* wqk = (o < 8) ? (Wq + r * 512 * 8 + o) : (Wk + r * 512 * 8 + (o - 8));
    const float* bvp = bv + r * 512;
    float s = (o < 8) ? bq[r * 8 + o] : bk[r * 8 + (o - 8)];
    for (int j = 0; j < 512; j++) s += bvp[j] * wqk[j * 8];
    FB[tid] = s;
  }
}

// ================= bucket-partitioned CSR build =================
// bucket = dst >> 7 (128 nodes per bucket), per relation.

// -- count edges per bucket via per-block LDS histogram --
__global__ void kb_count(const int* __restrict__ d1, const int* __restrict__ d2,
                         const int* __restrict__ d3, int* __restrict__ BC) {
  __shared__ int h[NBK];
  int tid = threadIdx.x;
  int r = blockIdx.y;
  const int* d = (r == 0) ? d1 : (r == 1) ? d2 : d3;
  for (int b = tid; b < NBK; b += 256) h[b] = 0;
  __syncthreads();
  for (int e = blockIdx.x * 256 + tid; e < EDG; e += 256 * gridDim.x)
    atomicAdd(&h[d[e] >> 7], 1);
  __syncthreads();
  for (int b = tid; b < NBK; b += 256)
    if (h[b]) atomicAdd(&BC[r * NBK + b], h[b]);
}

// -- exclusive scan of TOTB bucket counts (one block) --
__global__ void kb_scan(const int* __restrict__ BC, int* __restrict__ BB,
                        int* __restrict__ BCUR, int* __restrict__ rp) {
  __shared__ int a[2][2048];
  int t = threadIdx.x;   // 1024
  a[0][t]        = (t < TOTB) ? BC[t] : 0;
  a[0][t + 1024] = (t + 1024 < TOTB) ? BC[t + 1024] : 0;
  __syncthreads();
  int s = 0;
  for (int off = 1; off < 2048; off <<= 1) {
    int v0 = a[s][t];        if (t >= off) v0 += a[s][t - off];
    int v1 = a[s][t + 1024]; if (t + 1024 >= off) v1 += a[s][t + 1024 - off];
    __syncthreads();
    a[s ^ 1][t] = v0; a[s ^ 1][t + 1024] = v1;
    __syncthreads();
    s ^= 1;
  }
  if (t < TOTB)        { int e = a[s][t] - BC[t];               BB[t] = e;        BCUR[t] = e; }
  if (t + 1024 < TOTB) { int e = a[s][t + 1024] - BC[t + 1024]; BB[t + 1024] = e; BCUR[t + 1024] = e; }
  if (t == 0) rp[3 * NND] = 3 * EDG;
}

// -- scatter edges into bucket regions as packed (dstLow<<16 | src) --
__global__ void __launch_bounds__(256) kb_scatter(
    const int* __restrict__ s1, const int* __restrict__ d1,
    const int* __restrict__ s2, const int* __restrict__ d2,
    const int* __restrict__ s3, const int* __restrict__ d3,
    int* __restrict__ BCUR, unsigned* __restrict__ pairs) {
  __shared__ int h[NBK];
  __shared__ int bbase[NBK];
  int tid = threadIdx.x;
  int r = blockIdx.y;
  const int* dp = (r == 0) ? d1 : (r == 1) ? d2 : d3;
  const int* sp = (r == 0) ? s1 : (r == 1) ? s2 : s3;
  int e0 = blockIdx.x * TS;
  int n = EDG - e0; if (n > TS) n = TS;
  for (int b = tid; b < NBK; b += 256) h[b] = 0;
  __syncthreads();
  int eb[16]; unsigned ev[16];
#pragma unroll
  for (int k = 0; k < 16; k++) {
    int i = k * 256 + tid;
    if (i < n) {
      int d = dp[e0 + i], ss = sp[e0 + i];
      eb[k] = d >> 7;
      ev[k] = ((unsigned)(d & 127) << 16) | (unsigned)ss;
      atomicAdd(&h[eb[k]], 1);
    } else eb[k] = -1;
  }
  __syncthreads();
  for (int b = tid; b < NBK; b += 256) {
    int c = h[b];
    bbase[b] = c ? atomicAdd(&BCUR[r * NBK + b], c) : 0;
  }
  __syncthreads();
  for (int b = tid; b < NBK; b += 256) h[b] = 0;   // reuse as local cursor
  __syncthreads();
#pragma unroll
  for (int k = 0; k < 16; k++) {
    if (eb[k] >= 0) {
      int off = atomicAdd(&h[eb[k]], 1);
      pairs[bbase[eb[k]] + off] = ev[k];
    }
  }
}

// -- per-bucket: group into csrc + emit rowptr --
__global__ void __launch_bounds__(256) kb_build(
    const unsigned* __restrict__ pairs, const int* __restrict__ BB,
    const int* __restrict__ BC, int* __restrict__ rp, int* __restrict__ csrc) {
  __shared__ int cntl[128];
  __shared__ int sc[128];
  __shared__ int curl[128];
  int t = threadIdx.x;
  int r = blockIdx.y, bx = blockIdx.x;
  int bin = r * NBK + bx;
  int base = BB[bin], cnt = BC[bin];
  int node0 = bx << 7;
  int nloc = NND - node0; if (nloc > 128) nloc = 128;
  if (t < 128) cntl[t] = 0;
  __syncthreads();
  for (int i = t; i < cnt; i += 256)
    atomicAdd(&cntl[pairs[base + i] >> 16], 1);
  __syncthreads();
  if (t < 128) sc[t] = cntl[t];
  __syncthreads();
  for (int off = 1; off < 128; off <<= 1) {
    int v = 0;
    if (t < 128) { v = sc[t]; if (t >= off) v += sc[t - off]; }
    __syncthreads();
    if (t < 128) sc[t] = v;
    __syncthreads();
  }
  if (t < 128) {
    int excl = sc[t] - cntl[t];
    if (t < nloc) rp[r * NND + node0 + t] = base + excl;
    curl[t] = base + excl;
  }
  __syncthreads();
  for (int i = t; i < cnt; i += 256) {
    unsigned v = pairs[base + i];
    int p = atomicAdd(&curl[v >> 16], 1);
    csrc[p] = (int)(v & 0xFFFFu);
  }
}

// ---------------- bf16 MFMA GEMM: C[M,512] = bf16(A_f32[M,256]) @ Bt[512,256]^T + bias ----------------
__global__ void __launch_bounds__(256) k_gemm(const float* __restrict__ A, const u16* __restrict__ Bt,
                                              const float* __restrict__ bias, u16* __restrict__ C, int M) {
  __shared__ u16 sA[128 * 40];
  __shared__ u16 sB[128 * 40];
  int tid = threadIdx.x;
  int lane = tid & 63, wid = tid >> 6;
  int wm = wid >> 1, wn = wid & 1;
  int l15 = lane & 15, l4 = lane >> 4;
  int m0 = blockIdx.x * 128, n0 = blockIdx.y * 128;
  f32x4 acc[4][4] = {};
  for (int ko = 0; ko < 256; ko += 32) {
#pragma unroll
    for (int p = 0; p < 2; p++) {
      int idx = p * 256 + tid;
      int row = idx >> 2, seg = idx & 3;
      int gm = m0 + row; if (gm >= M) gm = M - 1;
      float4 a0 = *(const float4*)(A + (size_t)gm * 256 + ko + seg * 8);
      float4 a1 = *(const float4*)(A + (size_t)gm * 256 + ko + seg * 8 + 4);
      s16x8 av;
      av[0] = (short)f2b(a0.x); av[1] = (short)f2b(a0.y);
      av[2] = (short)f2b(a0.z); av[3] = (short)f2b(a0.w);
      av[4] = (short)f2b(a1.x); av[5] = (short)f2b(a1.y);
      av[6] = (short)f2b(a1.z); av[7] = (short)f2b(a1.w);
      *(s16x8*)&sA[row * 40 + seg * 8] = av;
      *(s16x8*)&sB[row * 40 + seg * 8] = *(const s16x8*)(Bt + (n0 + row) * 256 + ko + seg * 8);
    }
    __syncthreads();
    s16x8 af[4], bf[4];
#pragma unroll
    for (int i = 0; i < 4; i++) af[i] = *(const s16x8*)&sA[(wm * 64 + i * 16 + l15) * 40 + l4 * 8];
#pragma unroll
    for (int j = 0; j < 4; j++) bf[j] = *(const s16x8*)&sB[(wn * 64 + j * 16 + l15) * 40 + l4 * 8];
#pragma unroll
    for (int i = 0; i < 4; i++)
#pragma unroll
      for (int j = 0; j < 4; j++)
        acc[i][j] = __builtin_amdgcn_mfma_f32_16x16x32_bf16(af[i], bf[j], acc[i][j], 0, 0, 0);
    __syncthreads();
  }
#pragma unroll
  for (int j = 0; j < 4; j++) {
    int n = n0 + wn * 64 + j * 16 + l15;
    float bb = bias[n];
#pragma unroll
    for (int i = 0; i < 4; i++) {
      int mb = m0 + wm * 64 + i * 16 + l4 * 4;
#pragma unroll
      for (int r = 0; r < 4; r++) {
        int m = mb + r;
        if (m < M) C[(size_t)m * 512 + n] = f2b(acc[i][j][r] + bb);
      }
    }
  }
}

// ---------------- q/k logits straight from fp32 x via fused weights ----------------
__global__ void k_qk(const float* __restrict__ x, const float* __restrict__ FW,
                     const float* __restrict__ FB, float* __restrict__ qout,
                     float* __restrict__ kout, int N) {
  int lane = threadIdx.x & 63, wid = threadIdx.x >> 6;
  int stride = gridDim.x * 4;
  for (int row = blockIdx.x * 4 + wid; row < N; row += stride) {
    float4 xv = *(const float4*)(x + (size_t)row * 256 + lane * 4);
    float p[16];
#pragma unroll
    for (int o = 0; o < 16; o++) {
      float4 wv = *(const float4*)(FW + o * 256 + lane * 4);
      p[o] = xv.x * wv.x + xv.y * wv.y + xv.z * wv.z + xv.w * wv.w;
    }
#pragma unroll
    for (int off = 1; off < 64; off <<= 1)
#pragma unroll
      for (int o = 0; o < 16; o++) p[o] += __shfl_xor(p[o], off, 64);
    if (lane == 0) {
      if (qout) {
#pragma unroll
        for (int o = 0; o < 8; o++) qout[row * 8 + o] = p[o] + FB[o];
      }
      if (kout) {
#pragma unroll
        for (int o = 0; o < 8; o++) kout[row * 8 + o] = p[o + 8] + FB[o + 8];
      }
    }
  }
}

// ---------------- edge aggregation: one wave per dst node ----------------
__global__ void __launch_bounds__(256) k_edge(const int* __restrict__ rp, const int* __restrict__ csrc,
                       const float* __restrict__ q, const float* __restrict__ k,
                       const u16* __restrict__ hs, float* __restrict__ out,
                       float scale, int accum) {
  __shared__ float exw[4][64 * 8];
  __shared__ int sarr[4][64];
  int lane = threadIdx.x & 63, w = threadIdx.x >> 6;
  int dst = blockIdx.x * 4 + w;
  if (dst >= NND) return;
  int beg = rp[dst];
  int deg = rp[dst + 1] - beg;
  float qv[8];
  {
    float4 q0 = *(const float4*)(q + dst * 8);
    float4 q1 = *(const float4*)(q + dst * 8 + 4);
    qv[0] = q0.x; qv[1] = q0.y; qv[2] = q0.z; qv[3] = q0.w;
    qv[4] = q1.x; qv[5] = q1.y; qv[6] = q1.z; qv[7] = q1.w;
  }
  float dsum[8] = {0, 0, 0, 0, 0, 0, 0, 0};
  for (int base = 0; base < deg; base += 64) {
    int i = base + lane;
    if (i < deg) {
      int s = csrc[beg + i];
      float4 k0 = *(const float4*)(k + s * 8);
      float4 k1 = *(const float4*)(k + s * 8 + 4);
      float kv[8] = {k0.x, k0.y, k0.z, k0.w, k1.x, k1.y, k1.z, k1.w};
#pragma unroll
      for (int h = 0; h < 8; h++) {
        float e = qv[h] + kv[h];
        e = e > 0.f ? e : 0.2f * e;
        dsum[h] += exp2f(e * 1.44269504f);
      }
    }
  }
#pragma unroll
  for (int off = 1; off < 64; off <<= 1)
#pragma unroll
    for (int h = 0; h < 8; h++) dsum[h] += __shfl_xor(dsum[h], off, 64);
  float rden[8];
#pragma unroll
  for (int h = 0; h < 8; h++) rden[h] = dsum[h] > 0.f ? 1.f / dsum[h] : 0.f;

  float acc8[8] = {0, 0, 0, 0, 0, 0, 0, 0};
  for (int base = 0; base < deg; base += 64) {
    int i = base + lane;
    int nn = min(64, deg - base);
    if (i < deg) {
      int s = csrc[beg + i];
      sarr[w][lane] = s;
      float4 k0 = *(const float4*)(k + s * 8);
      float4 k1 = *(const float4*)(k + s * 8 + 4);
      float kv[8] = {k0.x, k0.y, k0.z, k0.w, k1.x, k1.y, k1.z, k1.w};
#pragma unroll
      for (int h = 0; h < 8; h++) {
        float e = qv[h] + kv[h];
        e = e > 0.f ? e : 0.2f * e;
        exw[w][lane * 8 + h] = exp2f(e * 1.44269504f) * rden[h];
      }
    }
    __asm__ __volatile__("s_waitcnt lgkmcnt(0)" ::: "memory");
    for (int j = 0; j < nn; j++) {
      int s = sarr[w][j];
      const u16* hp = hs + (size_t)s * 512 + lane;
      float4 e0 = *(const float4*)&exw[w][j * 8];
      float4 e1 = *(const float4*)&exw[w][j * 8 + 4];
      acc8[0] += e0.x * b2f(hp[0 * 64]);
      acc8[1] += e0.y * b2f(hp[1 * 64]);
      acc8[2] += e0.z * b2f(hp[2 * 64]);
      acc8[3] += e0.w * b2f(hp[3 * 64]);
      acc8[4] += e1.x * b2f(hp[4 * 64]);
      acc8[5] += e1.y * b2f(hp[5 * 64]);
      acc8[6] += e1.z * b2f(hp[6 * 64]);
      acc8[7] += e1.w * b2f(hp[7 * 64]);
    }
  }
  float acc = ((acc8[0] + acc8[1]) + (acc8[2] + acc8[3])) + ((acc8[4] + acc8[5]) + (acc8[6] + acc8[7]));
  acc *= scale;
  if (accum) out[dst * 64 + lane] += acc;
  else out[dst * 64 + lane] = acc;
}

extern "C" void kernel_launch(void* const* d_in, const int* in_sizes, int n_in,
                              void* d_out, int out_size, void* d_ws, size_t ws_size,
                              hipStream_t stream) {
  const float* xu = (const float*)d_in[0];
  const float* xi = (const float*)d_in[1];
  const float* Wv = (const float*)d_in[2];
  const float* bv = (const float*)d_in[3];
  const float* Wq = (const float*)d_in[4];
  const float* bq = (const float*)d_in[5];
  const float* Wk = (const float*)d_in[6];
  const float* bk = (const float*)d_in[7];
  const int* src1 = (const int*)d_in[8];
  const int* dst1 = (const int*)d_in[9];
  const int* src2 = (const int*)d_in[10];
  const int* dst2 = (const int*)d_in[11];
  const int* src3 = (const int*)d_in[12];
  const int* dst3 = (const int*)d_in[13];
  float* out_user = (float*)d_out;
  float* out_item = out_user + (size_t)NND * 64;

  char* w = (char*)d_ws;
  auto alloc = [&](size_t sz) -> char* {
    char* p = w; w += (sz + 255) & ~(size_t)255; return p;
  };
  // total ~83 MB
  u16* H    = (u16*)alloc((size_t)NND * 512 * 2);          // 51.2 MB shared h table
  u16* WT   = (u16*)alloc((size_t)3 * 512 * 256 * 2);      // 0.8 MB
  float* FW = (float*)alloc((size_t)3 * 16 * 256 * 4);     // 49 KB fused qk weights
  float* FB = (float*)alloc((size_t)3 * 16 * 4);
  float* Q0 = (float*)alloc((size_t)NND * 8 * 4);
  float* K0 = (float*)alloc((size_t)NND * 8 * 4);
  float* Q1 = (float*)alloc((size_t)NND * 8 * 4);
  float* K1 = (float*)alloc((size_t)NND * 8 * 4);
  float* Q2 = (float*)alloc((size_t)NND * 8 * 4);
  float* K2 = (float*)alloc((size_t)NND * 8 * 4);          // 9.6 MB total q/k
  int* ROWPTR = (int*)alloc(((size_t)3 * NND + 1) * 4);
  int* BC   = (int*)alloc(TOTB * 4);
  int* BB   = (int*)alloc(TOTB * 4);
  int* BCUR = (int*)alloc(TOTB * 4);
  int* CSRC = (int*)alloc((size_t)3 * EDG * 4);            // 19.2 MB
  unsigned* PAIRS = (unsigned*)H;                          // aliased: dead before H written
  (void)ws_size; (void)n_in; (void)in_sizes; (void)out_size;

  // --- CSR build (bucket partition) ---
  k_zero<<<(TOTB + 255) / 256, 256, 0, stream>>>(BC, TOTB);
  kb_count<<<dim3(256, 3), 256, 0, stream>>>(dst1, dst2, dst3, BC);
  kb_scan<<<1, 1024, 0, stream>>>(BC, BB, BCUR, ROWPTR);
  kb_scatter<<<dim3((EDG + TS - 1) / TS, 3), 256, 0, stream>>>(src1, dst1, src2, dst2, src3, dst3, BCUR, PAIRS);
  kb_build<<<dim3(NBK, 3), 256, 0, stream>>>(PAIRS, BB, BC, ROWPTR, CSRC);

  // --- weight prep ---
  k_prepw<<<(3 * 512 * 256 + 255) / 256, 256, 0, stream>>>(Wv, WT);
  k_fusew<<<48, 256, 0, stream>>>(Wv, bv, Wq, bq, Wk, bk, FW, FB);

  // --- q/k logits (direct from fp32 x, fused weights) ---
  k_qk<<<1024, 256, 0, stream>>>(xi, FW,        FB,      Q0, nullptr, NND);  // rel0 q (dst=item)
  k_qk<<<1024, 256, 0, stream>>>(xu, FW,        FB,      nullptr, K0, NND);  // rel0 k (src=user)
  k_qk<<<1024, 256, 0, stream>>>(xu, FW + 4096, FB + 16, Q1, nullptr, NND);  // rel1 q (dst=user)
  k_qk<<<1024, 256, 0, stream>>>(xi, FW + 4096, FB + 16, nullptr, K1, NND);  // rel1 k (src=item)
  k_qk<<<1024, 256, 0, stream>>>(xu, FW + 8192, FB + 32, Q2, K2, NND);       // rel2 (user->user)

  // --- per relation: GEMM into shared H, then edge aggregation ---
  dim3 gg((NND + 127) / 128, 4);
  k_gemm<<<gg, 256, 0, stream>>>(xu, WT,                 bv,        H, NND);
  k_edge<<<NND / 4, 256, 0, stream>>>(ROWPTR,           CSRC, Q0, K0, H, out_item, 0.125f,  0);
  k_gemm<<<gg, 256, 0, stream>>>(xi, WT + 512 * 256,     bv + 512,  H, NND);
  k_edge<<<NND / 4, 256, 0, stream>>>(ROWPTR + NND,     CSRC, Q1, K1, H, out_user, 0.0625f, 0);
  k_gemm<<<gg, 256, 0, stream>>>(xu, WT + 2 * 512 * 256, bv + 1024, H, NND);
  k_edge<<<NND / 4, 256, 0, stream>>>(ROWPTR + 2 * NND, CSRC, Q2, K2, H, out_user, 0.0625f, 1);
}